// Round 8
// baseline (467.860 us; speedup 1.0000x reference)
//
#include <hip/hip_runtime.h>
#include <hip/hip_bf16.h>
#include <cstdint>
#include <cstddef>

// B=8, N=4096, C=768, NUM_HEADS=8, HEAD_DIM=96, BN = 32768

#define GLOAD_LDS16(g, l) \
  __builtin_amdgcn_global_load_lds((const __attribute__((address_space(1))) void*)(g), \
                                   (__attribute__((address_space(3))) void*)(l), 16, 0, 0)

typedef __attribute__((ext_vector_type(8))) short bf16x8;
typedef __attribute__((ext_vector_type(4))) float f32x4;

__device__ __forceinline__ ushort f2bf(float f) {
  union { float f; uint32_t u; } v; v.f = f;
  uint32_t r = v.u + 0x7fffu + ((v.u >> 16) & 1u);   // RTNE
  return (ushort)(r >> 16);
}
__device__ __forceinline__ float bf2f(ushort u) {
  union { uint32_t x; float f; } v; v.x = (uint32_t)u << 16; return v.f;
}

// ---------- K0: f32 -> bf16 convert (weights only now) ----------
__global__ __launch_bounds__(256) void k_conv(const float* __restrict__ src,
                                              ushort* __restrict__ dst, int n4) {
  int i = blockIdx.x * blockDim.x + threadIdx.x;
  int stride = gridDim.x * blockDim.x;
  for (; i < n4; i += stride) {
    float4 v = ((const float4*)src)[i];
    ushort4 o;
    o.x = f2bf(v.x); o.y = f2bf(v.y); o.z = f2bf(v.z); o.w = f2bf(v.w);
    ((ushort4*)dst)[i] = o;
  }
}

// ---------- softplus(scale_p) -> 1/scale ----------
__global__ void k_softplus(const float* __restrict__ p, float* __restrict__ sinv) {
  int i = threadIdx.x + blockIdx.x * 256;
  if (i < 768) {
    float x = p[i];
    float s = (x > 20.f) ? x : log1pf(expf(x));
    sinv[i] = 1.0f / s;
  }
}

// ---------- GEMM: C[M][Nc] = A[M][768] * Bt[Nc][768] ----------
// BF16OUT: bf16 C (no bias). CONVA: A is f32, converted in-staging.
// 1-D grid + bijective XCD swizzle (nwg % 8 == 0): same-A-panel blocks -> same XCD.
template <bool BF16OUT, bool CONVA>
__global__ __launch_bounds__(256, 2) void gemm_bt(
    const void* __restrict__ Av, const ushort* __restrict__ Bt,
    void* __restrict__ Cv, const float* __restrict__ bias, int Ncols, int nbx) {
  constexpr int K = 768, BK = 64;
  __shared__ ushort lA[128 * BK];
  __shared__ ushort lB[128 * BK];
  const int tid  = threadIdx.x;
  const int lane = tid & 63;
  const int w    = tid >> 6;
  const int wr   = w >> 1, wc = w & 1;
  const int cpx  = gridDim.x >> 3;
  const int swz  = (blockIdx.x & 7) * cpx + (blockIdx.x >> 3);
  const int m0 = (swz / nbx) * 128;
  const int n0 = (swz % nbx) * 128;
  const int sr = lane >> 3;
  const int sc = (lane & 7) * 8;

  f32x4 acc[4][4] = {};

  for (int kt = 0; kt < K / BK; ++kt) {
    const int k0 = kt * BK;
    __syncthreads();
#pragma unroll
    for (int i = 0; i < 4; ++i) {
      const int ci = w * 4 + i;
      const int r  = ci * 8 + sr;
      if constexpr (CONVA) {
        const float* src = (const float*)Av + (size_t)(m0 + r) * K + (k0 + sc);
        float4 v0 = *(const float4*)src;
        float4 v1 = *(const float4*)(src + 4);
        ushort4 o0, o1;
        o0.x = f2bf(v0.x); o0.y = f2bf(v0.y); o0.z = f2bf(v0.z); o0.w = f2bf(v0.w);
        o1.x = f2bf(v1.x); o1.y = f2bf(v1.y); o1.z = f2bf(v1.z); o1.w = f2bf(v1.w);
        *(ushort4*)&lA[ci * 512 + lane * 8]     = o0;
        *(ushort4*)&lA[ci * 512 + lane * 8 + 4] = o1;
      } else {
        GLOAD_LDS16((const ushort*)Av + (size_t)(m0 + r) * K + (k0 + sc), lA + ci * 512);
      }
      GLOAD_LDS16(Bt + (size_t)(n0 + r) * K + (k0 + sc), lB + ci * 512);
    }
    __syncthreads();
#pragma unroll
    for (int kk = 0; kk < BK / 32; ++kk) {
      bf16x8 af[4], bfr[4];
#pragma unroll
      for (int m = 0; m < 4; ++m)
        af[m] = *(const bf16x8*)&lA[(wr * 64 + m * 16 + (lane & 15)) * BK + kk * 32 + (lane >> 4) * 8];
#pragma unroll
      for (int n = 0; n < 4; ++n)
        bfr[n] = *(const bf16x8*)&lB[(wc * 64 + n * 16 + (lane & 15)) * BK + kk * 32 + (lane >> 4) * 8];
#pragma unroll
      for (int m = 0; m < 4; ++m)
#pragma unroll
        for (int n = 0; n < 4; ++n)
          acc[m][n] = __builtin_amdgcn_mfma_f32_16x16x32_bf16(af[m], bfr[n], acc[m][n], 0, 0, 0);
    }
  }
#pragma unroll
  for (int n = 0; n < 4; ++n) {
    const int col = n0 + wc * 64 + n * 16 + (lane & 15);
    const float bv = (!BF16OUT && bias) ? bias[col] : 0.0f;
#pragma unroll
    for (int m = 0; m < 4; ++m) {
      const int row0 = m0 + wr * 64 + m * 16 + (lane >> 4) * 4;
#pragma unroll
      for (int j = 0; j < 4; ++j) {
        if (BF16OUT)
          ((ushort*)Cv)[(size_t)(row0 + j) * Ncols + col] = f2bf(acc[m][n][j]);
        else
          ((float*)Cv)[(size_t)(row0 + j) * Ncols + col] = acc[m][n][j] + bv;
      }
    }
  }
}

// ---------- K4: fused A-dot + G/ksum partials; wave-per-row, NO atomics ----------
__global__ __launch_bounds__(256) void k_gks(const ushort* __restrict__ qk,
                                             const float* __restrict__ pos,
                                             const float* __restrict__ wg,
                                             const float* __restrict__ sinv,
                                             float* __restrict__ part,
                                             float* __restrict__ partW) {
  __shared__ float pG[4][768];
  __shared__ float pK[4][768];
  __shared__ float lsq[4];
  const int tid = threadIdx.x, lane = tid & 63, w = tid >> 6;
  const int c0 = lane * 12;
  float sv[12], wv[12], ga[12] = {}, ka[12] = {};
#pragma unroll
  for (int v = 0; v < 3; ++v) {
    float4 s = *(const float4*)(sinv + c0 + v * 4);
    float4 g = *(const float4*)(wg + c0 + v * 4);
#pragma unroll
    for (int e = 0; e < 4; ++e) { sv[v * 4 + e] = (&s.x)[e]; wv[v * 4 + e] = (&g.x)[e]; }
  }
  float wsq = 0.f;
  for (int r = 0; r < 8; ++r) {
    const int row = blockIdx.x * 32 + w * 8 + r;
    const ushort* qr = qk + (size_t)row * 1536;
    const float* pr = pos + (size_t)(row & 4095) * 768;
    float q[12], kk[12], u[12];
    float d = 0.f, s1 = 0.f, s2 = 0.f;
#pragma unroll
    for (int v = 0; v < 3; ++v) {
      ushort4 qv = *(const ushort4*)(qr + c0 + v * 4);
      ushort4 kv = *(const ushort4*)(qr + 768 + c0 + v * 4);
      float4 pv = *(const float4*)(pr + c0 + v * 4);
#pragma unroll
      for (int e = 0; e < 4; ++e) {
        const int j = v * 4 + e;
        q[j] = bf2f((&qv.x)[e]);
        kk[j] = bf2f((&kv.x)[e]) + (&pv.x)[e];
      }
    }
#pragma unroll
    for (int j = 0; j < 12; ++j) {
      d += q[j] * wv[j];
      float t = (fmaxf(kk[j], 0.f) + 1e-6f) * sv[j];
      float uu = t * t * t;
      u[j] = uu;
      s1 += t * t; s2 += uu * uu;
    }
#pragma unroll
    for (int m = 32; m; m >>= 1) {
      d += __shfl_xor(d, m); s1 += __shfl_xor(s1, m); s2 += __shfl_xor(s2, m);
    }
    const float ratio = sqrtf(s1 / s2);
    wsq += d * d;
#pragma unroll
    for (int j = 0; j < 12; ++j) { ka[j] += u[j] * ratio; ga[j] += d * q[j]; }
  }
#pragma unroll
  for (int j = 0; j < 12; ++j) { pG[w][c0 + j] = ga[j]; pK[w][c0 + j] = ka[j]; }
  if (lane == 0) lsq[w] = wsq;
  __syncthreads();
  float* outp = part + (size_t)blockIdx.x * 1536;
  for (int i = tid; i < 768; i += 256) {
    outp[i]       = pG[0][i] + pG[1][i] + pG[2][i] + pG[3][i];
    outp[768 + i] = pK[0][i] + pK[1][i] + pK[2][i] + pK[3][i];
  }
  if (tid == 0) partW[blockIdx.x] = lsq[0] + lsq[1] + lsq[2] + lsq[3];
}

// ---------- K3: rnorm[b] from 128 wsq partials ----------
__global__ __launch_bounds__(256) void k_rnorm(const float* __restrict__ partW,
                                               float* __restrict__ rnorm) {
  const int tid = threadIdx.x;
  const int b = tid >> 5, j = tid & 31;
  float s = 0.f;
#pragma unroll
  for (int v = 0; v < 4; ++v) s += partW[b * 128 + j * 4 + v];
#pragma unroll
  for (int m = 16; m; m >>= 1) s += __shfl_xor(s, m);
  if (j == 0) {
    const float sf = 0.10206207261596575f;  // 96^-0.5
    rnorm[b] = sf / fmaxf(sf * sqrtf(s), 1e-12f);
  }
}

// ---------- K5: reduce 128 block-partials -> G (scaled), ksum ----------
__global__ __launch_bounds__(256) void k_gred(const float* __restrict__ part,
                                              const float* __restrict__ rnorm,
                                              float* __restrict__ G,
                                              float* __restrict__ ksum) {
  const int i = blockIdx.x * 256 + threadIdx.x;   // 0..1535
  const int b = blockIdx.y;
  const float* p = part + (size_t)b * 128 * 1536 + i;
  float s = 0.f;
#pragma unroll 8
  for (int blk = 0; blk < 128; ++blk) s += p[(size_t)blk * 1536];
  if (i < 768) G[b * 768 + i] = s * rnorm[b];
  else         ksum[b * 768 + i - 768] = s;
}

// ---------- K6: wave-per-row -> y (bf16) ----------
__global__ __launch_bounds__(256) void k_y(const ushort* __restrict__ qk,
                                           const float* __restrict__ G,
                                           const float* __restrict__ ksum,
                                           const float* __restrict__ sinv,
                                           ushort* __restrict__ y) {
  const int tid = threadIdx.x, lane = tid & 63, w = tid >> 6;
  const int row = blockIdx.x * 4 + w;
  const int b = row >> 12;
  const int c0 = lane * 12;
  const ushort* qr = qk + (size_t)row * 1536;
  float kk[12], u[12], ks[12], gg[12];
  float s1 = 0.f, s2 = 0.f;
#pragma unroll
  for (int v = 0; v < 3; ++v) {
    ushort4 qv = *(const ushort4*)(qr + c0 + v * 4);
    ushort4 kv = *(const ushort4*)(qr + 768 + c0 + v * 4);
    float4 sv = *(const float4*)(sinv + c0 + v * 4);
    float4 kv2 = *(const float4*)(ksum + b * 768 + c0 + v * 4);
    float4 gv = *(const float4*)(G + b * 768 + c0 + v * 4);
#pragma unroll
    for (int e = 0; e < 4; ++e) {
      const int j = v * 4 + e;
      kk[j] = bf2f((&kv.x)[e]);
      float t = (fmaxf(bf2f((&qv.x)[e]), 0.f) + 1e-6f) * (&sv.x)[e];
      float uu = t * t * t;
      u[j] = uu; s1 += t * t; s2 += uu * uu;
      ks[j] = (&kv2.x)[e]; gg[j] = (&gv.x)[e];
    }
  }
#pragma unroll
  for (int m = 32; m; m >>= 1) { s1 += __shfl_xor(s1, m); s2 += __shfl_xor(s2, m); }
  const float ratio = sqrtf(s1 / s2);
  float zp = 0.f;
#pragma unroll
  for (int j = 0; j < 12; ++j) zp += u[j] * ks[j];
  zp += __shfl_xor(zp, 1); zp += __shfl_xor(zp, 2); zp += __shfl_xor(zp, 4);  // head (8 lanes)
  const float z = 1.0f / (ratio * zp * (1.0f / 4096.0f) + 1e-6f);
  ushort o[12];
#pragma unroll
  for (int j = 0; j < 12; ++j) o[j] = f2bf(gg[j] * kk[j] * z);
  ushort* yp = y + (size_t)row * 768 + c0;
#pragma unroll
  for (int v = 0; v < 3; ++v)
    *(ushort4*)(yp + v * 4) = *(ushort4*)(o + v * 4);
}

// ---------- launcher ----------
extern "C" void kernel_launch(void* const* d_in, const int* in_sizes, int n_in,
                              void* d_out, int out_size, void* d_ws, size_t ws_size,
                              hipStream_t stream) {
  const float* x      = (const float*)d_in[0];
  const float* Wq     = (const float*)d_in[3];
  const float* Wkv    = (const float*)d_in[4];
  const float* Wproj  = (const float*)d_in[5];
  const float* bproj  = (const float*)d_in[6];
  const float* wg     = (const float*)d_in[7];
  const float* scalep = (const float*)d_in[8];
  const float* pos    = (const float*)d_in[9];

  char* ws = (char*)d_ws;
  ushort* qk   = (ushort*)ws;                         // 32768*1536 bf16 = 96 MiB
  float*  part = (float*)(ws + 100663296);            // 6.3 MiB
  ushort* ybf  = (ushort*)(ws + 100663296);           // 48 MiB, aliases part (dead by k_y)
  ushort* wqk  = (ushort*)(ws + 150994944);           // 2.25 MiB
  ushort* wpj  = (ushort*)(ws + 153354240);           // 1.125 MiB
  float*  sinv = (float*)(ws + 154533888);            // 768 f32
  float*  partW = (float*)(ws + 154536960);           // 1024 f32
  float*  accb  = (float*)(ws + 154541056);
  float* Gv     = accb;                               // 6144
  float* ksum   = accb + 6144;                        // 6144
  float* rnorm  = accb + 12288;                       // 8

  k_conv<<<576, 256, 0, stream>>>(Wq, wqk, 589824 / 4);
  k_conv<<<576, 256, 0, stream>>>(Wkv, wqk + 589824, 589824 / 4);
  k_conv<<<576, 256, 0, stream>>>(Wproj, wpj, 589824 / 4);
  k_softplus<<<3, 256, 0, stream>>>(scalep, sinv);

  // GEMM1: A = x (f32, converted in-staging), out = qk bf16. grid 3072, XCD-swizzled.
  gemm_bt<true, true><<<3072, 256, 0, stream>>>(x, wqk, qk, nullptr, 1536, 12);

  k_gks<<<1024, 256, 0, stream>>>(qk, pos, wg, sinv, part, partW);
  k_rnorm<<<1, 256, 0, stream>>>(partW, rnorm);
  k_gred<<<dim3(6, 8), 256, 0, stream>>>(part, rnorm, Gv, ksum);
  k_y<<<8192, 256, 0, stream>>>(qk, Gv, ksum, sinv, ybf);

  // GEMM2: A = ybf bf16, out = d_out f32 (+bias). grid 1536, XCD-swizzled.
  gemm_bt<false, false><<<1536, 256, 0, stream>>>(ybf, wpj, d_out, bproj, 768, 6);
}

// Round 9
// 398.190 us; speedup vs baseline: 1.1750x; 1.1750x over previous
//
#include <hip/hip_runtime.h>
#include <hip/hip_bf16.h>
#include <cstdint>
#include <cstddef>

// B=8, N=4096, C=768, NUM_HEADS=8, HEAD_DIM=96, BN = 32768

#define GLOAD_LDS16(g, l) \
  __builtin_amdgcn_global_load_lds((const __attribute__((address_space(1))) void*)(g), \
                                   (__attribute__((address_space(3))) void*)(l), 16, 0, 0)

typedef __attribute__((ext_vector_type(8))) short bf16x8;
typedef __attribute__((ext_vector_type(4))) float f32x4;

__device__ __forceinline__ ushort f2bf(float f) {
  union { float f; uint32_t u; } v; v.f = f;
  uint32_t r = v.u + 0x7fffu + ((v.u >> 16) & 1u);   // RTNE
  return (ushort)(r >> 16);
}
__device__ __forceinline__ float bf2f(ushort u) {
  union { uint32_t x; float f; } v; v.x = (uint32_t)u << 16; return v.f;
}

// ---------- K0: f32 -> bf16 convert ----------
__global__ __launch_bounds__(256) void k_conv(const float* __restrict__ src,
                                              ushort* __restrict__ dst, int n4) {
  int i = blockIdx.x * blockDim.x + threadIdx.x;
  int stride = gridDim.x * blockDim.x;
  for (; i < n4; i += stride) {
    float4 v = ((const float4*)src)[i];
    ushort4 o;
    o.x = f2bf(v.x); o.y = f2bf(v.y); o.z = f2bf(v.z); o.w = f2bf(v.w);
    ((ushort4*)dst)[i] = o;
  }
}

// ---------- softplus(scale_p) -> 1/scale ----------
__global__ void k_softplus(const float* __restrict__ p, float* __restrict__ sinv) {
  int i = threadIdx.x + blockIdx.x * 256;
  if (i < 768) {
    float x = p[i];
    float s = (x > 20.f) ? x : log1pf(expf(x));
    sinv[i] = 1.0f / s;
  }
}

// ---------- GEMM: C[M][Nc] = A[M][768] * Bt[Nc][768] ----------
// BF16OUT: bf16 C (no bias). A is bf16, staged via global_load_lds (async).
// 1-D grid + bijective XCD swizzle (nwg % 8 == 0): same-A-panel blocks -> same XCD.
template <bool BF16OUT>
__global__ __launch_bounds__(256, 2) void gemm_bt(
    const ushort* __restrict__ A, const ushort* __restrict__ Bt,
    void* __restrict__ Cv, const float* __restrict__ bias, int Ncols, int nbx) {
  constexpr int K = 768, BK = 64;
  __shared__ ushort lA[128 * BK];
  __shared__ ushort lB[128 * BK];
  const int tid  = threadIdx.x;
  const int lane = tid & 63;
  const int w    = tid >> 6;
  const int wr   = w >> 1, wc = w & 1;
  const int cpx  = gridDim.x >> 3;
  const int swz  = (blockIdx.x & 7) * cpx + (blockIdx.x >> 3);
  const int m0 = (swz / nbx) * 128;
  const int n0 = (swz % nbx) * 128;
  const int sr = lane >> 3;
  const int sc = (lane & 7) * 8;

  f32x4 acc[4][4] = {};

  for (int kt = 0; kt < K / BK; ++kt) {
    const int k0 = kt * BK;
    __syncthreads();
#pragma unroll
    for (int i = 0; i < 4; ++i) {
      const int ci = w * 4 + i;
      const int r  = ci * 8 + sr;
      GLOAD_LDS16(A  + (size_t)(m0 + r) * K + (k0 + sc), lA + ci * 512);
      GLOAD_LDS16(Bt + (size_t)(n0 + r) * K + (k0 + sc), lB + ci * 512);
    }
    __syncthreads();
#pragma unroll
    for (int kk = 0; kk < BK / 32; ++kk) {
      bf16x8 af[4], bfr[4];
#pragma unroll
      for (int m = 0; m < 4; ++m)
        af[m] = *(const bf16x8*)&lA[(wr * 64 + m * 16 + (lane & 15)) * BK + kk * 32 + (lane >> 4) * 8];
#pragma unroll
      for (int n = 0; n < 4; ++n)
        bfr[n] = *(const bf16x8*)&lB[(wc * 64 + n * 16 + (lane & 15)) * BK + kk * 32 + (lane >> 4) * 8];
#pragma unroll
      for (int m = 0; m < 4; ++m)
#pragma unroll
        for (int n = 0; n < 4; ++n)
          acc[m][n] = __builtin_amdgcn_mfma_f32_16x16x32_bf16(af[m], bfr[n], acc[m][n], 0, 0, 0);
    }
  }
#pragma unroll
  for (int n = 0; n < 4; ++n) {
    const int col = n0 + wc * 64 + n * 16 + (lane & 15);
    const float bv = (!BF16OUT && bias) ? bias[col] : 0.0f;
#pragma unroll
    for (int m = 0; m < 4; ++m) {
      const int row0 = m0 + wr * 64 + m * 16 + (lane >> 4) * 4;
#pragma unroll
      for (int j = 0; j < 4; ++j) {
        if (BF16OUT)
          ((ushort*)Cv)[(size_t)(row0 + j) * Ncols + col] = f2bf(acc[m][n][j]);
        else
          ((float*)Cv)[(size_t)(row0 + j) * Ncols + col] = acc[m][n][j] + bv;
      }
    }
  }
}

// ---------- K4: fused A-dot + G/ksum partials; wave-per-row, NO atomics ----------
__global__ __launch_bounds__(256) void k_gks(const ushort* __restrict__ qk,
                                             const float* __restrict__ pos,
                                             const float* __restrict__ wg,
                                             const float* __restrict__ sinv,
                                             float* __restrict__ part,
                                             float* __restrict__ partW) {
  __shared__ float pG[4][768];
  __shared__ float pK[4][768];
  __shared__ float lsq[4];
  const int tid = threadIdx.x, lane = tid & 63, w = tid >> 6;
  const int c0 = lane * 12;
  float sv[12], wv[12], ga[12] = {}, ka[12] = {};
#pragma unroll
  for (int v = 0; v < 3; ++v) {
    float4 s = *(const float4*)(sinv + c0 + v * 4);
    float4 g = *(const float4*)(wg + c0 + v * 4);
#pragma unroll
    for (int e = 0; e < 4; ++e) { sv[v * 4 + e] = (&s.x)[e]; wv[v * 4 + e] = (&g.x)[e]; }
  }
  float wsq = 0.f;
  for (int r = 0; r < 8; ++r) {
    const int row = blockIdx.x * 32 + w * 8 + r;
    const ushort* qr = qk + (size_t)row * 1536;
    const float* pr = pos + (size_t)(row & 4095) * 768;
    float q[12], kk[12], u[12];
    float d = 0.f, s1 = 0.f, s2 = 0.f;
#pragma unroll
    for (int v = 0; v < 3; ++v) {
      ushort4 qv = *(const ushort4*)(qr + c0 + v * 4);
      ushort4 kv = *(const ushort4*)(qr + 768 + c0 + v * 4);
      float4 pv = *(const float4*)(pr + c0 + v * 4);
#pragma unroll
      for (int e = 0; e < 4; ++e) {
        const int j = v * 4 + e;
        q[j] = bf2f((&qv.x)[e]);
        kk[j] = bf2f((&kv.x)[e]) + (&pv.x)[e];
      }
    }
#pragma unroll
    for (int j = 0; j < 12; ++j) {
      d += q[j] * wv[j];
      float t = (fmaxf(kk[j], 0.f) + 1e-6f) * sv[j];
      float uu = t * t * t;
      u[j] = uu;
      s1 += t * t; s2 += uu * uu;
    }
#pragma unroll
    for (int m = 32; m; m >>= 1) {
      d += __shfl_xor(d, m); s1 += __shfl_xor(s1, m); s2 += __shfl_xor(s2, m);
    }
    const float ratio = sqrtf(s1 / s2);
    wsq += d * d;
#pragma unroll
    for (int j = 0; j < 12; ++j) { ka[j] += u[j] * ratio; ga[j] += d * q[j]; }
  }
#pragma unroll
  for (int j = 0; j < 12; ++j) { pG[w][c0 + j] = ga[j]; pK[w][c0 + j] = ka[j]; }
  if (lane == 0) lsq[w] = wsq;
  __syncthreads();
  float* outp = part + (size_t)blockIdx.x * 1536;
  for (int i = tid; i < 768; i += 256) {
    outp[i]       = pG[0][i] + pG[1][i] + pG[2][i] + pG[3][i];
    outp[768 + i] = pK[0][i] + pK[1][i] + pK[2][i] + pK[3][i];
  }
  if (tid == 0) partW[blockIdx.x] = lsq[0] + lsq[1] + lsq[2] + lsq[3];
}

// ---------- K3: rnorm[b] from 128 wsq partials ----------
__global__ __launch_bounds__(256) void k_rnorm(const float* __restrict__ partW,
                                               float* __restrict__ rnorm) {
  const int tid = threadIdx.x;
  const int b = tid >> 5, j = tid & 31;
  float s = 0.f;
#pragma unroll
  for (int v = 0; v < 4; ++v) s += partW[b * 128 + j * 4 + v];
#pragma unroll
  for (int m = 16; m; m >>= 1) s += __shfl_xor(s, m);
  if (j == 0) {
    const float sf = 0.10206207261596575f;  // 96^-0.5
    rnorm[b] = sf / fmaxf(sf * sqrtf(s), 1e-12f);
  }
}

// ---------- K5: reduce 128 block-partials -> G (scaled), ksum ----------
__global__ __launch_bounds__(256) void k_gred(const float* __restrict__ part,
                                              const float* __restrict__ rnorm,
                                              float* __restrict__ G,
                                              float* __restrict__ ksum) {
  const int i = blockIdx.x * 256 + threadIdx.x;   // 0..1535
  const int b = blockIdx.y;
  const float* p = part + (size_t)b * 128 * 1536 + i;
  float s = 0.f;
#pragma unroll 8
  for (int blk = 0; blk < 128; ++blk) s += p[(size_t)blk * 1536];
  if (i < 768) G[b * 768 + i] = s * rnorm[b];
  else         ksum[b * 768 + i - 768] = s;
}

// ---------- K6: wave-per-row -> y (bf16) ----------
__global__ __launch_bounds__(256) void k_y(const ushort* __restrict__ qk,
                                           const float* __restrict__ G,
                                           const float* __restrict__ ksum,
                                           const float* __restrict__ sinv,
                                           ushort* __restrict__ y) {
  const int tid = threadIdx.x, lane = tid & 63, w = tid >> 6;
  const int row = blockIdx.x * 4 + w;
  const int b = row >> 12;
  const int c0 = lane * 12;
  const ushort* qr = qk + (size_t)row * 1536;
  float kk[12], u[12], ks[12], gg[12];
  float s1 = 0.f, s2 = 0.f;
#pragma unroll
  for (int v = 0; v < 3; ++v) {
    ushort4 qv = *(const ushort4*)(qr + c0 + v * 4);
    ushort4 kv = *(const ushort4*)(qr + 768 + c0 + v * 4);
    float4 sv = *(const float4*)(sinv + c0 + v * 4);
    float4 kv2 = *(const float4*)(ksum + b * 768 + c0 + v * 4);
    float4 gv = *(const float4*)(G + b * 768 + c0 + v * 4);
#pragma unroll
    for (int e = 0; e < 4; ++e) {
      const int j = v * 4 + e;
      kk[j] = bf2f((&kv.x)[e]);
      float t = (fmaxf(bf2f((&qv.x)[e]), 0.f) + 1e-6f) * (&sv.x)[e];
      float uu = t * t * t;
      u[j] = uu; s1 += t * t; s2 += uu * uu;
      ks[j] = (&kv2.x)[e]; gg[j] = (&gv.x)[e];
    }
  }
#pragma unroll
  for (int m = 32; m; m >>= 1) { s1 += __shfl_xor(s1, m); s2 += __shfl_xor(s2, m); }
  const float ratio = sqrtf(s1 / s2);
  float zp = 0.f;
#pragma unroll
  for (int j = 0; j < 12; ++j) zp += u[j] * ks[j];
  zp += __shfl_xor(zp, 1); zp += __shfl_xor(zp, 2); zp += __shfl_xor(zp, 4);  // head (8 lanes)
  const float z = 1.0f / (ratio * zp * (1.0f / 4096.0f) + 1e-6f);
  ushort o[12];
#pragma unroll
  for (int j = 0; j < 12; ++j) o[j] = f2bf(gg[j] * kk[j] * z);
  ushort* yp = y + (size_t)row * 768 + c0;
#pragma unroll
  for (int v = 0; v < 3; ++v)
    *(ushort4*)(yp + v * 4) = *(ushort4*)(o + v * 4);
}

// ---------- launcher ----------
extern "C" void kernel_launch(void* const* d_in, const int* in_sizes, int n_in,
                              void* d_out, int out_size, void* d_ws, size_t ws_size,
                              hipStream_t stream) {
  const float* x      = (const float*)d_in[0];
  const float* Wq     = (const float*)d_in[3];
  const float* Wkv    = (const float*)d_in[4];
  const float* Wproj  = (const float*)d_in[5];
  const float* bproj  = (const float*)d_in[6];
  const float* wg     = (const float*)d_in[7];
  const float* scalep = (const float*)d_in[8];
  const float* pos    = (const float*)d_in[9];

  char* ws = (char*)d_ws;
  ushort* qk   = (ushort*)ws;                         // 32768*1536 bf16 = 96 MiB
  ushort* xbf  = (ushort*)(ws + 100663296);           // 48 MiB; reused: part, then y
  ushort* ybf  = xbf;
  float*  part = (float*)(ws + 100663296);            // 6.3 MiB; xbf dead after gemm1,
                                                      // part dead (k_gred) before k_y writes ybf
  ushort* wqk  = (ushort*)(ws + 150994944);           // 2.25 MiB
  ushort* wpj  = (ushort*)(ws + 153354240);           // 1.125 MiB
  float*  sinv = (float*)(ws + 154533888);            // 768 f32
  float*  partW = (float*)(ws + 154536960);           // 1024 f32
  float*  accb  = (float*)(ws + 154541056);
  float* Gv     = accb;                               // 6144
  float* ksum   = accb + 6144;                        // 6144
  float* rnorm  = accb + 12288;                       // 8

  k_conv<<<4096, 256, 0, stream>>>(x, xbf, 25165824 / 4);
  k_conv<<<576, 256, 0, stream>>>(Wq, wqk, 589824 / 4);
  k_conv<<<576, 256, 0, stream>>>(Wkv, wqk + 589824, 589824 / 4);
  k_conv<<<576, 256, 0, stream>>>(Wproj, wpj, 589824 / 4);
  k_softplus<<<3, 256, 0, stream>>>(scalep, sinv);

  // GEMM1: A = xbf (bf16), out = qk bf16. grid 3072 1-D, XCD-swizzled.
  gemm_bt<true><<<3072, 256, 0, stream>>>(xbf, wqk, qk, nullptr, 1536, 12);

  k_gks<<<1024, 256, 0, stream>>>(qk, pos, wg, sinv, part, partW);
  k_rnorm<<<1, 256, 0, stream>>>(partW, rnorm);
  k_gred<<<dim3(6, 8), 256, 0, stream>>>(part, rnorm, Gv, ksum);
  k_y<<<8192, 256, 0, stream>>>(qk, Gv, ksum, sinv, ybf);

  // GEMM2: A = ybf bf16, out = d_out f32 (+bias). grid 1536 1-D, XCD-swizzled.
  gemm_bt<false><<<1536, 256, 0, stream>>>(ybf, wpj, d_out, bproj, 768, 6);
}

// Round 10
// 395.052 us; speedup vs baseline: 1.1843x; 1.0079x over previous
//
#include <hip/hip_runtime.h>
#include <hip/hip_bf16.h>
#include <cstdint>
#include <cstddef>

// B=8, N=4096, C=768, NUM_HEADS=8, HEAD_DIM=96, BN = 32768

#define GLOAD_LDS16(g, l) \
  __builtin_amdgcn_global_load_lds((const __attribute__((address_space(1))) void*)(g), \
                                   (__attribute__((address_space(3))) void*)(l), 16, 0, 0)

typedef __attribute__((ext_vector_type(8))) short bf16x8;
typedef __attribute__((ext_vector_type(4))) float f32x4;

__device__ __forceinline__ ushort f2bf(float f) {
  union { float f; uint32_t u; } v; v.f = f;
  uint32_t r = v.u + 0x7fffu + ((v.u >> 16) & 1u);   // RTNE
  return (ushort)(r >> 16);
}
__device__ __forceinline__ float bf2f(ushort u) {
  union { uint32_t x; float f; } v; v.x = (uint32_t)u << 16; return v.f;
}

// ---------- K0: f32 -> bf16 convert ----------
__global__ __launch_bounds__(256) void k_conv(const float* __restrict__ src,
                                              ushort* __restrict__ dst, int n4) {
  int i = blockIdx.x * blockDim.x + threadIdx.x;
  int stride = gridDim.x * blockDim.x;
  for (; i < n4; i += stride) {
    float4 v = ((const float4*)src)[i];
    ushort4 o;
    o.x = f2bf(v.x); o.y = f2bf(v.y); o.z = f2bf(v.z); o.w = f2bf(v.w);
    ((ushort4*)dst)[i] = o;
  }
}

// ---------- softplus(scale_p) -> 1/scale ----------
__global__ void k_softplus(const float* __restrict__ p, float* __restrict__ sinv) {
  int i = threadIdx.x + blockIdx.x * 256;
  if (i < 768) {
    float x = p[i];
    float s = (x > 20.f) ? x : log1pf(expf(x));
    sinv[i] = 1.0f / s;
  }
}

// ---------- GEMM: C[M][Nc] = A[M][768] * Bt[Nc][768] ----------
// launch_bounds(256,4): LDS 32KB permits 5 blocks/CU; probe whether occupancy was the 37% cap.
template <bool BF16OUT>
__global__ __launch_bounds__(256, 4) void gemm_bt(
    const ushort* __restrict__ A, const ushort* __restrict__ Bt,
    void* __restrict__ Cv, const float* __restrict__ bias, int Ncols, int nbx) {
  constexpr int K = 768, BK = 64;
  __shared__ ushort lA[128 * BK];
  __shared__ ushort lB[128 * BK];
  const int tid  = threadIdx.x;
  const int lane = tid & 63;
  const int w    = tid >> 6;
  const int wr   = w >> 1, wc = w & 1;
  const int cpx  = gridDim.x >> 3;
  const int swz  = (blockIdx.x & 7) * cpx + (blockIdx.x >> 3);
  const int m0 = (swz / nbx) * 128;
  const int n0 = (swz % nbx) * 128;
  const int sr = lane >> 3;
  const int sc = (lane & 7) * 8;

  f32x4 acc[4][4] = {};

  for (int kt = 0; kt < K / BK; ++kt) {
    const int k0 = kt * BK;
    __syncthreads();
#pragma unroll
    for (int i = 0; i < 4; ++i) {
      const int ci = w * 4 + i;
      const int r  = ci * 8 + sr;
      GLOAD_LDS16(A  + (size_t)(m0 + r) * K + (k0 + sc), lA + ci * 512);
      GLOAD_LDS16(Bt + (size_t)(n0 + r) * K + (k0 + sc), lB + ci * 512);
    }
    __syncthreads();
#pragma unroll
    for (int kk = 0; kk < BK / 32; ++kk) {
      bf16x8 af[4], bfr[4];
#pragma unroll
      for (int m = 0; m < 4; ++m)
        af[m] = *(const bf16x8*)&lA[(wr * 64 + m * 16 + (lane & 15)) * BK + kk * 32 + (lane >> 4) * 8];
#pragma unroll
      for (int n = 0; n < 4; ++n)
        bfr[n] = *(const bf16x8*)&lB[(wc * 64 + n * 16 + (lane & 15)) * BK + kk * 32 + (lane >> 4) * 8];
#pragma unroll
      for (int m = 0; m < 4; ++m)
#pragma unroll
        for (int n = 0; n < 4; ++n)
          acc[m][n] = __builtin_amdgcn_mfma_f32_16x16x32_bf16(af[m], bfr[n], acc[m][n], 0, 0, 0);
    }
  }
#pragma unroll
  for (int n = 0; n < 4; ++n) {
    const int col = n0 + wc * 64 + n * 16 + (lane & 15);
    const float bv = (!BF16OUT && bias) ? bias[col] : 0.0f;
#pragma unroll
    for (int m = 0; m < 4; ++m) {
      const int row0 = m0 + wr * 64 + m * 16 + (lane >> 4) * 4;
#pragma unroll
      for (int j = 0; j < 4; ++j) {
        if (BF16OUT)
          ((ushort*)Cv)[(size_t)(row0 + j) * Ncols + col] = f2bf(acc[m][n][j]);
        else
          ((float*)Cv)[(size_t)(row0 + j) * Ncols + col] = acc[m][n][j] + bv;
      }
    }
  }
}

// ---------- K4: fused A-dot + G/ksum partials; coalesced 16B loads, NO atomics ----------
// Channel partition (no head structure needed): lane owns cA=8*lane..+7 and cB=512+4*lane..+3.
__global__ __launch_bounds__(256) void k_gks(const ushort* __restrict__ qk,
                                             const float* __restrict__ pos,
                                             const float* __restrict__ wg,
                                             const float* __restrict__ sinv,
                                             float* __restrict__ part,
                                             float* __restrict__ partW) {
  __shared__ float pG[4][768];
  __shared__ float pK[4][768];
  __shared__ float lsq[4];
  const int tid = threadIdx.x, lane = tid & 63, w = tid >> 6;
  const int cA = lane * 8;
  const int cB = 512 + lane * 4;
  float svA[8], svB[4], wvA[8], wvB[4];
  float gaA[8] = {}, gaB[4] = {}, kaA[8] = {}, kaB[4] = {};
  {
    float4 s0 = *(const float4*)(sinv + cA);
    float4 s1v = *(const float4*)(sinv + cA + 4);
    float4 s2v = *(const float4*)(sinv + cB);
    float4 g0 = *(const float4*)(wg + cA);
    float4 g1 = *(const float4*)(wg + cA + 4);
    float4 g2 = *(const float4*)(wg + cB);
#pragma unroll
    for (int e = 0; e < 4; ++e) {
      svA[e] = (&s0.x)[e]; svA[4 + e] = (&s1v.x)[e]; svB[e] = (&s2v.x)[e];
      wvA[e] = (&g0.x)[e]; wvA[4 + e] = (&g1.x)[e]; wvB[e] = (&g2.x)[e];
    }
  }
  float wsq = 0.f;
  for (int r = 0; r < 8; ++r) {
    const int row = blockIdx.x * 32 + w * 8 + r;
    const ushort* qr = qk + (size_t)row * 1536;
    const float* pr = pos + (size_t)(row & 4095) * 768;
    bf16x8 qv8 = *(const bf16x8*)(qr + cA);
    ushort4 qv4 = *(const ushort4*)(qr + cB);
    bf16x8 kv8 = *(const bf16x8*)(qr + 768 + cA);
    ushort4 kv4 = *(const ushort4*)(qr + 768 + cB);
    float4 p0 = *(const float4*)(pr + cA);
    float4 p1 = *(const float4*)(pr + cA + 4);
    float4 p2 = *(const float4*)(pr + cB);
    float qA[8], qB[4], uA[8], uB[4];
    float d = 0.f, s1 = 0.f, s2 = 0.f;
#pragma unroll
    for (int j = 0; j < 8; ++j) {
      qA[j] = bf2f((ushort)qv8[j]);
      float kkv = bf2f((ushort)kv8[j]) + ((j < 4) ? (&p0.x)[j] : (&p1.x)[j - 4]);
      d += qA[j] * wvA[j];
      float t = (fmaxf(kkv, 0.f) + 1e-6f) * svA[j];
      float uu = t * t * t;
      uA[j] = uu; s1 += t * t; s2 += uu * uu;
    }
#pragma unroll
    for (int j = 0; j < 4; ++j) {
      qB[j] = bf2f((&qv4.x)[j]);
      float kkv = bf2f((&kv4.x)[j]) + (&p2.x)[j];
      d += qB[j] * wvB[j];
      float t = (fmaxf(kkv, 0.f) + 1e-6f) * svB[j];
      float uu = t * t * t;
      uB[j] = uu; s1 += t * t; s2 += uu * uu;
    }
#pragma unroll
    for (int m = 32; m; m >>= 1) {
      d += __shfl_xor(d, m); s1 += __shfl_xor(s1, m); s2 += __shfl_xor(s2, m);
    }
    const float ratio = sqrtf(s1 / s2);
    wsq += d * d;
#pragma unroll
    for (int j = 0; j < 8; ++j) { kaA[j] += uA[j] * ratio; gaA[j] += d * qA[j]; }
#pragma unroll
    for (int j = 0; j < 4; ++j) { kaB[j] += uB[j] * ratio; gaB[j] += d * qB[j]; }
  }
#pragma unroll
  for (int j = 0; j < 8; ++j) { pG[w][cA + j] = gaA[j]; pK[w][cA + j] = kaA[j]; }
#pragma unroll
  for (int j = 0; j < 4; ++j) { pG[w][cB + j] = gaB[j]; pK[w][cB + j] = kaB[j]; }
  if (lane == 0) lsq[w] = wsq;
  __syncthreads();
  float* outp = part + (size_t)blockIdx.x * 1536;
  for (int i = tid; i < 768; i += 256) {
    outp[i]       = pG[0][i] + pG[1][i] + pG[2][i] + pG[3][i];
    outp[768 + i] = pK[0][i] + pK[1][i] + pK[2][i] + pK[3][i];
  }
  if (tid == 0) partW[blockIdx.x] = lsq[0] + lsq[1] + lsq[2] + lsq[3];
}

// ---------- K3: rnorm[b] from 128 wsq partials ----------
__global__ __launch_bounds__(256) void k_rnorm(const float* __restrict__ partW,
                                               float* __restrict__ rnorm) {
  const int tid = threadIdx.x;
  const int b = tid >> 5, j = tid & 31;
  float s = 0.f;
#pragma unroll
  for (int v = 0; v < 4; ++v) s += partW[b * 128 + j * 4 + v];
#pragma unroll
  for (int m = 16; m; m >>= 1) s += __shfl_xor(s, m);
  if (j == 0) {
    const float sf = 0.10206207261596575f;  // 96^-0.5
    rnorm[b] = sf / fmaxf(sf * sqrtf(s), 1e-12f);
  }
}

// ---------- K5: reduce 128 block-partials -> G (scaled), ksum ----------
__global__ __launch_bounds__(256) void k_gred(const float* __restrict__ part,
                                              const float* __restrict__ rnorm,
                                              float* __restrict__ G,
                                              float* __restrict__ ksum) {
  const int i = blockIdx.x * 256 + threadIdx.x;   // 0..1535
  const int b = blockIdx.y;
  const float* p = part + (size_t)b * 128 * 1536 + i;
  float s = 0.f;
#pragma unroll 8
  for (int blk = 0; blk < 128; ++blk) s += p[(size_t)blk * 1536];
  if (i < 768) G[b * 768 + i] = s * rnorm[b];
  else         ksum[b * 768 + i - 768] = s;
}

// ---------- K6: wave-per-row -> y (bf16); per-head 16B-aligned chunks ----------
// head h = lane>>3 (8 lanes/head). lane owns cA = 96h+8j (8ch) and cB = 96h+64+4j (4ch).
__global__ __launch_bounds__(256) void k_y(const ushort* __restrict__ qk,
                                           const float* __restrict__ G,
                                           const float* __restrict__ ksum,
                                           const float* __restrict__ sinv,
                                           ushort* __restrict__ y) {
  const int tid = threadIdx.x, lane = tid & 63, w = tid >> 6;
  const int row = blockIdx.x * 4 + w;
  const int b = row >> 12;
  const int h = lane >> 3, j8 = lane & 7;
  const int cA = h * 96 + j8 * 8;
  const int cB = h * 96 + 64 + j8 * 4;
  const ushort* qr = qk + (size_t)row * 1536;
  float kkA[8], kkB[4], uA[8], uB[4], ksA[8], ksB[4], ggA[8], ggB[4];
  float s1 = 0.f, s2 = 0.f;
  {
    bf16x8 qv8 = *(const bf16x8*)(qr + cA);
    ushort4 qv4 = *(const ushort4*)(qr + cB);
    bf16x8 kv8 = *(const bf16x8*)(qr + 768 + cA);
    ushort4 kv4 = *(const ushort4*)(qr + 768 + cB);
    float4 s0 = *(const float4*)(sinv + cA);
    float4 s1v = *(const float4*)(sinv + cA + 4);
    float4 s2v = *(const float4*)(sinv + cB);
    float4 k0 = *(const float4*)(ksum + b * 768 + cA);
    float4 k1 = *(const float4*)(ksum + b * 768 + cA + 4);
    float4 k2 = *(const float4*)(ksum + b * 768 + cB);
    float4 g0 = *(const float4*)(G + b * 768 + cA);
    float4 g1 = *(const float4*)(G + b * 768 + cA + 4);
    float4 g2 = *(const float4*)(G + b * 768 + cB);
#pragma unroll
    for (int j = 0; j < 8; ++j) {
      kkA[j] = bf2f((ushort)kv8[j]);
      float sv = (j < 4) ? (&s0.x)[j] : (&s1v.x)[j - 4];
      float t = (fmaxf(bf2f((ushort)qv8[j]), 0.f) + 1e-6f) * sv;
      float uu = t * t * t;
      uA[j] = uu; s1 += t * t; s2 += uu * uu;
      ksA[j] = (j < 4) ? (&k0.x)[j] : (&k1.x)[j - 4];
      ggA[j] = (j < 4) ? (&g0.x)[j] : (&g1.x)[j - 4];
    }
#pragma unroll
    for (int j = 0; j < 4; ++j) {
      kkB[j] = bf2f((&kv4.x)[j]);
      float t = (fmaxf(bf2f((&qv4.x)[j]), 0.f) + 1e-6f) * (&s2v.x)[j];
      float uu = t * t * t;
      uB[j] = uu; s1 += t * t; s2 += uu * uu;
      ksB[j] = (&k2.x)[j]; ggB[j] = (&g2.x)[j];
    }
  }
#pragma unroll
  for (int m = 32; m; m >>= 1) { s1 += __shfl_xor(s1, m); s2 += __shfl_xor(s2, m); }
  const float ratio = sqrtf(s1 / s2);
  float zp = 0.f;
#pragma unroll
  for (int j = 0; j < 8; ++j) zp += uA[j] * ksA[j];
#pragma unroll
  for (int j = 0; j < 4; ++j) zp += uB[j] * ksB[j];
  zp += __shfl_xor(zp, 1); zp += __shfl_xor(zp, 2); zp += __shfl_xor(zp, 4);  // head (8 lanes)
  const float z = 1.0f / (ratio * zp * (1.0f / 4096.0f) + 1e-6f);
  ushort oA[8], oB[4];
#pragma unroll
  for (int j = 0; j < 8; ++j) oA[j] = f2bf(ggA[j] * kkA[j] * z);
#pragma unroll
  for (int j = 0; j < 4; ++j) oB[j] = f2bf(ggB[j] * kkB[j] * z);
  ushort* yp = y + (size_t)row * 768;
  *(ushort4*)(yp + cA)     = *(ushort4*)(oA);
  *(ushort4*)(yp + cA + 4) = *(ushort4*)(oA + 4);
  *(ushort4*)(yp + cB)     = *(ushort4*)(oB);
}

// ---------- launcher ----------
extern "C" void kernel_launch(void* const* d_in, const int* in_sizes, int n_in,
                              void* d_out, int out_size, void* d_ws, size_t ws_size,
                              hipStream_t stream) {
  const float* x      = (const float*)d_in[0];
  const float* Wq     = (const float*)d_in[3];
  const float* Wkv    = (const float*)d_in[4];
  const float* Wproj  = (const float*)d_in[5];
  const float* bproj  = (const float*)d_in[6];
  const float* wg     = (const float*)d_in[7];
  const float* scalep = (const float*)d_in[8];
  const float* pos    = (const float*)d_in[9];

  char* ws = (char*)d_ws;
  ushort* qk   = (ushort*)ws;                         // 96 MiB
  ushort* xbf  = (ushort*)(ws + 100663296);           // 48 MiB; reused: part, then y
  ushort* ybf  = xbf;
  float*  part = (float*)(ws + 100663296);
  ushort* wqk  = (ushort*)(ws + 150994944);
  ushort* wpj  = (ushort*)(ws + 153354240);
  float*  sinv = (float*)(ws + 154533888);
  float*  partW = (float*)(ws + 154536960);
  float*  accb  = (float*)(ws + 154541056);
  float* Gv     = accb;
  float* ksum   = accb + 6144;
  float* rnorm  = accb + 12288;

  k_conv<<<4096, 256, 0, stream>>>(x, xbf, 25165824 / 4);
  k_conv<<<576, 256, 0, stream>>>(Wq, wqk, 589824 / 4);
  k_conv<<<576, 256, 0, stream>>>(Wkv, wqk + 589824, 589824 / 4);
  k_conv<<<576, 256, 0, stream>>>(Wproj, wpj, 589824 / 4);
  k_softplus<<<3, 256, 0, stream>>>(scalep, sinv);

  gemm_bt<true><<<3072, 256, 0, stream>>>(xbf, wqk, qk, nullptr, 1536, 12);

  k_gks<<<1024, 256, 0, stream>>>(qk, pos, wg, sinv, part, partW);
  k_rnorm<<<1, 256, 0, stream>>>(partW, rnorm);
  k_gred<<<dim3(6, 8), 256, 0, stream>>>(part, rnorm, Gv, ksum);
  k_y<<<8192, 256, 0, stream>>>(qk, Gv, ksum, sinv, ybf);

  gemm_bt<false><<<1536, 256, 0, stream>>>(ybf, wpj, d_out, bproj, 768, 6);
}